// Round 18
// baseline (210.112 us; speedup 1.0000x reference)
//
#include <hip/hip_runtime.h>

typedef __bf16 bf16x8 __attribute__((ext_vector_type(8)));
typedef float  f32x4  __attribute__((ext_vector_type(4)));

// ---- LDS layout (bytes) ----  (r12/r15/r16 champion, unchanged)
// x : [96][256] bf16 swz  off=(m*512+2c)^((m&31)<<4)          [0,49152)
//     later y: [32][768] bf16 swz off=(p*1536+2k)^((p&31)<<4)  aliases x
// o : [2 hg][2 buf][96][40] bf16 (80B rows, 16B-aligned)       [49152,79872)
// after head loop (o dead): ps [96][4] f32 @49152, pq @50688, mu @52224, rs @52608
#define XOFF 0
#define OOFF 49152
#define OBUFSZ 7680
#define PSOFF 49152
#define PQOFF 50688
#define MUOFF 52224
#define RSOFF 52608
#define SMEM_BYTES 79872
#define OB(g,b) (smem + OOFF + ((g) * 2 + (b)) * OBUFSZ)

static __device__ __forceinline__ unsigned short f2b(float f) {
  __bf16 h = (__bf16)f;
  return __builtin_bit_cast(unsigned short, h);
}

__global__ void convert_weights(const float* __restrict__ w_in,
                                const float* __restrict__ w_out,
                                const float* __restrict__ w_conv,
                                __bf16* __restrict__ ws) {
  int gid = blockIdx.x * 256 + threadIdx.x;   // 0..114687
  int i4 = gid * 4;
  const float* src;
  int off;
  if (i4 < 196608)      { src = w_in;   off = i4; }
  else if (i4 < 262144) { src = w_out;  off = i4 - 196608; }
  else                  { src = w_conv; off = i4 - 262144; }
  float4 f = *(const float4*)(src + off);
  ws[i4 + 0] = (__bf16)f.x;
  ws[i4 + 1] = (__bf16)f.y;
  ws[i4 + 2] = (__bf16)f.z;
  ws[i4 + 3] = (__bf16)f.w;
}

__global__ __launch_bounds__(256, 2) void crf_fused(
    const float* __restrict__ cort,
    const float* __restrict__ subc,
    const float* __restrict__ vent,
    const __bf16* __restrict__ w_in,
    const float* __restrict__ b_in,
    const __bf16* __restrict__ w_out,
    const float* __restrict__ b_out,
    const float* __restrict__ gamma,
    const float* __restrict__ beta,
    const __bf16* __restrict__ w_conv,
    const float* __restrict__ b_conv,
    float* __restrict__ out) {
  extern __shared__ char smem[];
  const int tid  = threadIdx.x;
  const int lane = tid & 63;
  const int wv   = tid >> 6;
  const int l15  = lane & 15;
  const int l4   = lane >> 4;
  const int blk  = blockIdx.x;
  const int img  = blk >> 7;                 // 128 blocks per image
  const int pixbase = (blk & 127) << 5;      // 32 pixels per block
  const size_t base = (size_t)img * (256 * 4096) + pixbase;

  // ---------- stage x -> LDS bf16 [96][256] swz; float4 reads, packed dword writes ----------
  {
    const int p4 = (tid & 7) * 4;           // pixel quad
#pragma unroll
    for (int si = 0; si < 3; ++si) {
      const float* rp = (si == 0) ? cort : (si == 1) ? subc : vent;
      rp += base;
#pragma unroll
      for (int t = 0; t < 4; ++t) {
        int c = t * 64 + (tid >> 3) * 2;    // even channel
        float4 fa = *(const float4*)(rp + (size_t)c * 4096 + p4);
        float4 fb = *(const float4*)(rp + (size_t)(c + 1) * 4096 + p4);
#pragma unroll
        for (int k = 0; k < 4; ++k) {
          int m = si * 32 + p4 + k;
          float va = (k == 0) ? fa.x : (k == 1) ? fa.y : (k == 2) ? fa.z : fa.w;
          float vb = (k == 0) ? fb.x : (k == 1) ? fb.y : (k == 2) ? fb.z : fb.w;
          unsigned off = ((unsigned)(m * 512 + c * 2)) ^ ((unsigned)(m & 31) << 4);
          *(unsigned*)(smem + XOFF + off) = (unsigned)f2b(va) | ((unsigned)f2b(vb) << 16);
        }
      }
    }
  }

  f32x4 accY[6][4] = {};   // persistent out_proj accumulators: wave owns 64 N-cols, all 96 M-rows

  __syncthreads();   // B1

  const int ph = wv & 1;   // pixel half (16 pixels)
  const int hg = wv >> 1;  // head group (4 heads)
  const float SC = 0.17677669529663687f;  // 1/sqrt(32)

  for (int hh = 0; hh < 4; ++hh) {
    const int h = hg * 4 + hh;
    // hoisted bias loads (hide under QKV)
    float bq0 = b_in[h * 32 + l15],       bq1 = b_in[h * 32 + 16 + l15];
    float bk0 = b_in[256 + h * 32 + l15], bk1 = b_in[256 + h * 32 + 16 + l15];
    float bv0 = b_in[512 + h * 32 + l15], bv1 = b_in[512 + h * 32 + 16 + l15];

    // ---------- QKV GEMM for head h, this wave's 16 pixels ----------
    f32x4 acc[3][6] = {};   // [token s][0,1=q 2,3=k 4,5=v]
#pragma unroll
    for (int ks = 0; ks < 8; ++ks) {
      const int k0 = ks * 32;
      bf16x8 af[3], bfr[6];
#pragma unroll
      for (int s = 0; s < 3; ++s) {
        int m = s * 32 + ph * 16 + l15;
        unsigned off = ((unsigned)(m * 512 + (k0 + l4 * 8) * 2)) ^ ((unsigned)(m & 31) << 4);
        af[s] = *(const bf16x8*)(smem + XOFF + off);
      }
#pragma unroll
      for (int j = 0; j < 6; ++j) {
        int jb = (j >> 1) * 256 + h * 32 + (j & 1) * 16 + l15;
        bfr[j] = *(const bf16x8*)(w_in + (size_t)jb * 256 + k0 + l4 * 8);
      }
#pragma unroll
      for (int s = 0; s < 3; ++s)
#pragma unroll
        for (int j = 0; j < 6; ++j)
          acc[s][j] = __builtin_amdgcn_mfma_f32_16x16x32_bf16(af[s], bfr[j], acc[s][j], 0, 0, 0);
    }

    // ---------- PREFETCH w_out fragments for this iteration's out_proj (r15 win) ----------
    bf16x8 bfA[4], bfB[4];
#pragma unroll
    for (int j = 0; j < 4; ++j) {
      int jr = wv * 64 + j * 16 + l15;
      bfA[j] = *(const bf16x8*)(w_out + (size_t)jr * 256 + hh * 32 + l4 * 8);
      bfB[j] = *(const bf16x8*)(w_out + (size_t)jr * 256 + (4 + hh) * 32 + l4 * 8);
    }

#pragma unroll
    for (int s = 0; s < 3; ++s)
#pragma unroll
      for (int r = 0; r < 4; ++r) {
        acc[s][0][r] += bq0; acc[s][1][r] += bq1;
        acc[s][2][r] += bk0; acc[s][3][r] += bk1;
        acc[s][4][r] += bv0; acc[s][5][r] += bv1;
      }

    // ---------- in-register attention; lane holds d=jq*16+l15, pixel p=ph*16+l4*4+r ----------
    char* ob = OB(hg, hh & 1);
#pragma unroll
    for (int si = 0; si < 3; ++si) {
      float pp[3][4];
#pragma unroll
      for (int ti = 0; ti < 3; ++ti)
#pragma unroll
        for (int r = 0; r < 4; ++r)
          pp[ti][r] = acc[si][0][r] * acc[ti][2][r] + acc[si][1][r] * acc[ti][3][r];
#pragma unroll
      for (int mask = 1; mask <= 8; mask <<= 1)
#pragma unroll
        for (int ti = 0; ti < 3; ++ti)
#pragma unroll
          for (int r = 0; r < 4; ++r)
            pp[ti][r] += __shfl_xor(pp[ti][r], mask);
#pragma unroll
      for (int r = 0; r < 4; ++r) {
        float s0 = pp[0][r] * SC, s1 = pp[1][r] * SC, s2 = pp[2][r] * SC;
        float mx = fmaxf(fmaxf(s0, s1), s2);
        float e0 = __expf(s0 - mx), e1 = __expf(s1 - mx), e2 = __expf(s2 - mx);
        // v_rcp_f32 (rel err ~1e-5 << bf16 rounding) replaces the Newton divide
        float inv = __builtin_amdgcn_rcpf(e0 + e1 + e2);
        e0 *= inv; e1 *= inv; e2 *= inv;
        int m = si * 32 + ph * 16 + l4 * 4 + r;
#pragma unroll
        for (int jq = 0; jq < 2; ++jq) {
          float ov = e0 * acc[0][4 + jq][r] + e1 * acc[1][4 + jq][r] + e2 * acc[2][4 + jq][r];
          *(__bf16*)(ob + m * 80 + (jq * 16 + l15) * 2) = (__bf16)ov;
        }
      }
    }
    __syncthreads();   // single barrier/iter: writes(buf b) before reads(buf b); alternation guards reuse

    // ---------- out_proj partial: K-slices of heads hh and 4+hh (weights already in regs) ----------
    {
      const int b = hh & 1;
      bf16x8 afA[6], afB[6];
#pragma unroll
      for (int i = 0; i < 6; ++i) {
        int ro = (i * 16 + l15) * 80 + l4 * 16;
        afA[i] = *(const bf16x8*)(OB(0, b) + ro);
        afB[i] = *(const bf16x8*)(OB(1, b) + ro);
      }
#pragma unroll
      for (int i = 0; i < 6; ++i)
#pragma unroll
        for (int j = 0; j < 4; ++j) {
          accY[i][j] = __builtin_amdgcn_mfma_f32_16x16x32_bf16(afA[i], bfA[j], accY[i][j], 0, 0, 0);
          accY[i][j] = __builtin_amdgcn_mfma_f32_16x16x32_bf16(afB[i], bfB[j], accY[i][j], 0, 0, 0);
        }
    }
  }  // head loop

  // ---------- PREFETCH conv ks=0 weight fragments (hide under the whole LN phase; r16 win) ----------
  bf16x8 cafp[4];
#pragma unroll
  for (int i = 0; i < 4; ++i) {
    int co = wv * 64 + i * 16 + l15;
    cafp[i] = *(const bf16x8*)(w_conv + (size_t)co * 768 + l4 * 8);
  }

  __syncthreads();   // all out_proj o-reads done; o-region reusable for LN partials

  // ---------- bias + residual + LayerNorm partials ----------
  float bo[4], gg[4], bb2[4];
#pragma unroll
  for (int j = 0; j < 4; ++j) {
    int jc = wv * 64 + j * 16 + l15;
    bo[j] = b_out[jc];
    gg[j] = gamma[jc];
    bb2[j] = beta[jc];
  }
#pragma unroll
  for (int i = 0; i < 6; ++i)
#pragma unroll
    for (int r = 0; r < 4; ++r) {
      int m = i * 16 + l4 * 4 + r;
      float s1 = 0.f, s2 = 0.f;
#pragma unroll
      for (int j = 0; j < 4; ++j) {
        int jc = wv * 64 + j * 16 + l15;
        unsigned xo = ((unsigned)(m * 512 + jc * 2)) ^ ((unsigned)(m & 31) << 4);
        float xv = (float)(*(const __bf16*)(smem + XOFF + xo));
        float v = accY[i][j][r] + bo[j] + xv;
        accY[i][j][r] = v;
        s1 += v;
        s2 += v * v;
      }
      s1 += __shfl_xor(s1, 1); s2 += __shfl_xor(s2, 1);
      s1 += __shfl_xor(s1, 2); s2 += __shfl_xor(s2, 2);
      s1 += __shfl_xor(s1, 4); s2 += __shfl_xor(s2, 4);
      s1 += __shfl_xor(s1, 8); s2 += __shfl_xor(s2, 8);
      if (l15 == 0) {
        *(float*)(smem + PSOFF + (m * 4 + wv) * 4) = s1;
        *(float*)(smem + PQOFF + (m * 4 + wv) * 4) = s2;
      }
    }
  __syncthreads();
  if (tid < 96) {
    float s = 0.f, q = 0.f;
#pragma unroll
    for (int j = 0; j < 4; ++j) {
      s += *(const float*)(smem + PSOFF + (tid * 4 + j) * 4);
      q += *(const float*)(smem + PQOFF + (tid * 4 + j) * 4);
    }
    float mu  = s * (1.f / 256.f);
    float var = q * (1.f / 256.f) - mu * mu;
    *(float*)(smem + MUOFF + tid * 4) = mu;
    *(float*)(smem + RSOFF + tid * 4) = rsqrtf(var + 1e-5f);
  }
  __syncthreads();
  // rescale + write y bf16 into [32][768] swz (aliases x; all x reads done)
#pragma unroll
  for (int i = 0; i < 6; ++i)
#pragma unroll
    for (int r = 0; r < 4; ++r) {
      int m = i * 16 + l4 * 4 + r;
      float mu = *(const float*)(smem + MUOFF + m * 4);
      float rs = *(const float*)(smem + RSOFF + m * 4);
      int s = m >> 5, p = m & 31;
#pragma unroll
      for (int j = 0; j < 4; ++j) {
        int jc = wv * 64 + j * 16 + l15;
        float yv = (accY[i][j][r] - mu) * rs * gg[j] + bb2[j];
        int kk = s * 256 + jc;
        unsigned off = ((unsigned)(p * 1536 + kk * 2)) ^ ((unsigned)(p & 31) << 4);
        *(__bf16*)(smem + XOFF + off) = (__bf16)yv;
      }
    }
  __syncthreads();

  // ---------- 1x1 conv: M=cout(256, wave owns 64), N=pixel(32), K=768 ----------
  // 1-deep software pipeline: prefetch ks+1's w_conv fragments before ks's MFMAs (r16 win).
  {
    f32x4 accC[4][2] = {};
#pragma unroll 4
    for (int ks = 0; ks < 24; ++ks) {
      const int k0 = ks * 32;
      bf16x8 afn[4], bfr2[2];
      if (ks < 23) {
#pragma unroll
        for (int i = 0; i < 4; ++i) {
          int co = wv * 64 + i * 16 + l15;
          afn[i] = *(const bf16x8*)(w_conv + (size_t)co * 768 + (k0 + 32) + l4 * 8);
        }
      }
#pragma unroll
      for (int j = 0; j < 2; ++j) {
        int p = j * 16 + l15;
        unsigned off = ((unsigned)(p * 1536 + (k0 + l4 * 8) * 2)) ^ ((unsigned)(p & 31) << 4);
        bfr2[j] = *(const bf16x8*)(smem + XOFF + off);
      }
#pragma unroll
      for (int i = 0; i < 4; ++i)
#pragma unroll
        for (int j = 0; j < 2; ++j)
          accC[i][j] = __builtin_amdgcn_mfma_f32_16x16x32_bf16(cafp[i], bfr2[j], accC[i][j], 0, 0, 0);
      if (ks < 23) {
#pragma unroll
        for (int i = 0; i < 4; ++i) cafp[i] = afn[i];
      }
    }
#pragma unroll
    for (int i = 0; i < 4; ++i)
#pragma unroll
      for (int r = 0; r < 4; ++r) {
        int co = wv * 64 + i * 16 + l4 * 4 + r;
        float cb = b_conv[co];
#pragma unroll
        for (int j = 0; j < 2; ++j)
          out[((size_t)img * 256 + co) * 4096 + pixbase + j * 16 + l15] = accC[i][j][r] + cb;
      }
  }
}

extern "C" void kernel_launch(void* const* d_in, const int* in_sizes, int n_in,
                              void* d_out, int out_size, void* d_ws, size_t ws_size,
                              hipStream_t stream) {
  (void)in_sizes; (void)n_in; (void)out_size; (void)ws_size;
  const float* cort    = (const float*)d_in[0];
  const float* subc    = (const float*)d_in[1];
  const float* vent    = (const float*)d_in[2];
  const float* w_in_f  = (const float*)d_in[3];
  const float* b_in    = (const float*)d_in[4];
  const float* w_out_f = (const float*)d_in[5];
  const float* b_out   = (const float*)d_in[6];
  const float* gamma   = (const float*)d_in[7];
  const float* beta    = (const float*)d_in[8];
  const float* w_conv_f= (const float*)d_in[9];
  const float* b_conv  = (const float*)d_in[10];

  __bf16* ws = (__bf16*)d_ws;   // 458752 bf16 = 917504 B
  convert_weights<<<448, 256, 0, stream>>>(w_in_f, w_out_f, w_conv_f, ws);
  crf_fused<<<1024, 256, SMEM_BYTES, stream>>>(
      cort, subc, vent,
      ws,            b_in,
      ws + 196608,   b_out,
      gamma,         beta,
      ws + 262144,   b_conv,
      (float*)d_out);
}

// Round 19
// 195.403 us; speedup vs baseline: 1.0753x; 1.0753x over previous
//
#include <hip/hip_runtime.h>

typedef __bf16 bf16x8 __attribute__((ext_vector_type(8)));
typedef float  f32x4  __attribute__((ext_vector_type(4)));

// ---- LDS layout (bytes) ----  (r12/r15/r16 champion, unchanged)
// x : [96][256] bf16 swz  off=(m*512+2c)^((m&31)<<4)          [0,49152)
//     later y: [32][768] bf16 swz off=(p*1536+2k)^((p&31)<<4)  aliases x
// o : [2 hg][2 buf][96][40] bf16 (80B rows, 16B-aligned)       [49152,79872)
// after head loop (o dead): ps [96][4] f32 @49152, pq @50688, mu @52224, rs @52608
#define XOFF 0
#define OOFF 49152
#define OBUFSZ 7680
#define PSOFF 49152
#define PQOFF 50688
#define MUOFF 52224
#define RSOFF 52608
#define SMEM_BYTES 79872
#define OB(g,b) (smem + OOFF + ((g) * 2 + (b)) * OBUFSZ)

static __device__ __forceinline__ unsigned short f2b(float f) {
  __bf16 h = (__bf16)f;
  return __builtin_bit_cast(unsigned short, h);
}

__global__ void convert_weights(const float* __restrict__ w_in,
                                const float* __restrict__ w_out,
                                const float* __restrict__ w_conv,
                                __bf16* __restrict__ ws) {
  int gid = blockIdx.x * 256 + threadIdx.x;   // 0..114687
  int i4 = gid * 4;
  const float* src;
  int off;
  if (i4 < 196608)      { src = w_in;   off = i4; }
  else if (i4 < 262144) { src = w_out;  off = i4 - 196608; }
  else                  { src = w_conv; off = i4 - 262144; }
  float4 f = *(const float4*)(src + off);
  ws[i4 + 0] = (__bf16)f.x;
  ws[i4 + 1] = (__bf16)f.y;
  ws[i4 + 2] = (__bf16)f.z;
  ws[i4 + 3] = (__bf16)f.w;
}

__global__ __launch_bounds__(256, 2) void crf_fused(
    const float* __restrict__ cort,
    const float* __restrict__ subc,
    const float* __restrict__ vent,
    const __bf16* __restrict__ w_in,
    const float* __restrict__ b_in,
    const __bf16* __restrict__ w_out,
    const float* __restrict__ b_out,
    const float* __restrict__ gamma,
    const float* __restrict__ beta,
    const __bf16* __restrict__ w_conv,
    const float* __restrict__ b_conv,
    float* __restrict__ out) {
  extern __shared__ char smem[];
  const int tid  = threadIdx.x;
  const int lane = tid & 63;
  const int wv   = tid >> 6;
  const int l15  = lane & 15;
  const int l4   = lane >> 4;
  const int blk  = blockIdx.x;
  const int img  = blk >> 7;                 // 128 blocks per image
  const int pixbase = (blk & 127) << 5;      // 32 pixels per block
  const size_t base = (size_t)img * (256 * 4096) + pixbase;

  // ---------- stage x -> LDS bf16 [96][256] swz; float4 reads, packed dword writes ----------
  {
    const int p4 = (tid & 7) * 4;           // pixel quad
#pragma unroll
    for (int si = 0; si < 3; ++si) {
      const float* rp = (si == 0) ? cort : (si == 1) ? subc : vent;
      rp += base;
#pragma unroll
      for (int t = 0; t < 4; ++t) {
        int c = t * 64 + (tid >> 3) * 2;    // even channel
        float4 fa = *(const float4*)(rp + (size_t)c * 4096 + p4);
        float4 fb = *(const float4*)(rp + (size_t)(c + 1) * 4096 + p4);
#pragma unroll
        for (int k = 0; k < 4; ++k) {
          int m = si * 32 + p4 + k;
          float va = (k == 0) ? fa.x : (k == 1) ? fa.y : (k == 2) ? fa.z : fa.w;
          float vb = (k == 0) ? fb.x : (k == 1) ? fb.y : (k == 2) ? fb.z : fb.w;
          unsigned off = ((unsigned)(m * 512 + c * 2)) ^ ((unsigned)(m & 31) << 4);
          *(unsigned*)(smem + XOFF + off) = (unsigned)f2b(va) | ((unsigned)f2b(vb) << 16);
        }
      }
    }
  }

  f32x4 accY[6][4] = {};   // persistent out_proj accumulators: wave owns 64 N-cols, all 96 M-rows

  __syncthreads();   // B1

  const int ph = wv & 1;   // pixel half (16 pixels)
  const int hg = wv >> 1;  // head group (4 heads)
  const float SC = 0.17677669529663687f;  // 1/sqrt(32)

  for (int hh = 0; hh < 4; ++hh) {
    const int h = hg * 4 + hh;
    // hoisted bias loads (hide under QKV)
    float bq0 = b_in[h * 32 + l15],       bq1 = b_in[h * 32 + 16 + l15];
    float bk0 = b_in[256 + h * 32 + l15], bk1 = b_in[256 + h * 32 + 16 + l15];
    float bv0 = b_in[512 + h * 32 + l15], bv1 = b_in[512 + h * 32 + 16 + l15];

    // ---------- QKV GEMM for head h, this wave's 16 pixels ----------
    f32x4 acc[3][6] = {};   // [token s][0,1=q 2,3=k 4,5=v]
#pragma unroll
    for (int ks = 0; ks < 8; ++ks) {
      const int k0 = ks * 32;
      bf16x8 af[3], bfr[6];
#pragma unroll
      for (int s = 0; s < 3; ++s) {
        int m = s * 32 + ph * 16 + l15;
        unsigned off = ((unsigned)(m * 512 + (k0 + l4 * 8) * 2)) ^ ((unsigned)(m & 31) << 4);
        af[s] = *(const bf16x8*)(smem + XOFF + off);
      }
#pragma unroll
      for (int j = 0; j < 6; ++j) {
        int jb = (j >> 1) * 256 + h * 32 + (j & 1) * 16 + l15;
        bfr[j] = *(const bf16x8*)(w_in + (size_t)jb * 256 + k0 + l4 * 8);
      }
#pragma unroll
      for (int s = 0; s < 3; ++s)
#pragma unroll
        for (int j = 0; j < 6; ++j)
          acc[s][j] = __builtin_amdgcn_mfma_f32_16x16x32_bf16(af[s], bfr[j], acc[s][j], 0, 0, 0);
    }

    // ---------- PREFETCH w_out fragments for this iteration's out_proj (r15 win) ----------
    bf16x8 bfA[4], bfB[4];
#pragma unroll
    for (int j = 0; j < 4; ++j) {
      int jr = wv * 64 + j * 16 + l15;
      bfA[j] = *(const bf16x8*)(w_out + (size_t)jr * 256 + hh * 32 + l4 * 8);
      bfB[j] = *(const bf16x8*)(w_out + (size_t)jr * 256 + (4 + hh) * 32 + l4 * 8);
    }

#pragma unroll
    for (int s = 0; s < 3; ++s)
#pragma unroll
      for (int r = 0; r < 4; ++r) {
        acc[s][0][r] += bq0; acc[s][1][r] += bq1;
        acc[s][2][r] += bk0; acc[s][3][r] += bk1;
        acc[s][4][r] += bv0; acc[s][5][r] += bv1;
      }

    // ---------- in-register attention; lane holds d=jq*16+l15, pixel p=ph*16+l4*4+r ----------
    char* ob = OB(hg, hh & 1);
#pragma unroll
    for (int si = 0; si < 3; ++si) {
      float pp[3][4];
#pragma unroll
      for (int ti = 0; ti < 3; ++ti)
#pragma unroll
        for (int r = 0; r < 4; ++r)
          pp[ti][r] = acc[si][0][r] * acc[ti][2][r] + acc[si][1][r] * acc[ti][3][r];
#pragma unroll
      for (int mask = 1; mask <= 8; mask <<= 1)
#pragma unroll
        for (int ti = 0; ti < 3; ++ti)
#pragma unroll
          for (int r = 0; r < 4; ++r)
            pp[ti][r] += __shfl_xor(pp[ti][r], mask);
#pragma unroll
      for (int r = 0; r < 4; ++r) {
        float s0 = pp[0][r] * SC, s1 = pp[1][r] * SC, s2 = pp[2][r] * SC;
        float mx = fmaxf(fmaxf(s0, s1), s2);
        float e0 = __expf(s0 - mx), e1 = __expf(s1 - mx), e2 = __expf(s2 - mx);
        float inv = 1.f / (e0 + e1 + e2);
        e0 *= inv; e1 *= inv; e2 *= inv;
        int m = si * 32 + ph * 16 + l4 * 4 + r;
#pragma unroll
        for (int jq = 0; jq < 2; ++jq) {
          float ov = e0 * acc[0][4 + jq][r] + e1 * acc[1][4 + jq][r] + e2 * acc[2][4 + jq][r];
          *(__bf16*)(ob + m * 80 + (jq * 16 + l15) * 2) = (__bf16)ov;
        }
      }
    }
    __syncthreads();   // single barrier/iter: writes(buf b) before reads(buf b); alternation guards reuse

    // ---------- out_proj partial: K-slices of heads hh and 4+hh (weights already in regs) ----------
    {
      const int b = hh & 1;
      bf16x8 afA[6], afB[6];
#pragma unroll
      for (int i = 0; i < 6; ++i) {
        int ro = (i * 16 + l15) * 80 + l4 * 16;
        afA[i] = *(const bf16x8*)(OB(0, b) + ro);
        afB[i] = *(const bf16x8*)(OB(1, b) + ro);
      }
#pragma unroll
      for (int i = 0; i < 6; ++i)
#pragma unroll
        for (int j = 0; j < 4; ++j) {
          accY[i][j] = __builtin_amdgcn_mfma_f32_16x16x32_bf16(afA[i], bfA[j], accY[i][j], 0, 0, 0);
          accY[i][j] = __builtin_amdgcn_mfma_f32_16x16x32_bf16(afB[i], bfB[j], accY[i][j], 0, 0, 0);
        }
    }
  }  // head loop

  // ---------- PREFETCH conv ks=0 weight fragments (hide under the whole LN phase; r16 win) ----------
  bf16x8 cafp[4];
#pragma unroll
  for (int i = 0; i < 4; ++i) {
    int co = wv * 64 + i * 16 + l15;
    cafp[i] = *(const bf16x8*)(w_conv + (size_t)co * 768 + l4 * 8);
  }

  __syncthreads();   // all out_proj o-reads done; o-region reusable for LN partials

  // ---------- bias + residual + LayerNorm partials ----------
  float bo[4], gg[4], bb2[4];
#pragma unroll
  for (int j = 0; j < 4; ++j) {
    int jc = wv * 64 + j * 16 + l15;
    bo[j] = b_out[jc];
    gg[j] = gamma[jc];
    bb2[j] = beta[jc];
  }
#pragma unroll
  for (int i = 0; i < 6; ++i)
#pragma unroll
    for (int r = 0; r < 4; ++r) {
      int m = i * 16 + l4 * 4 + r;
      float s1 = 0.f, s2 = 0.f;
#pragma unroll
      for (int j = 0; j < 4; ++j) {
        int jc = wv * 64 + j * 16 + l15;
        unsigned xo = ((unsigned)(m * 512 + jc * 2)) ^ ((unsigned)(m & 31) << 4);
        float xv = (float)(*(const __bf16*)(smem + XOFF + xo));
        float v = accY[i][j][r] + bo[j] + xv;
        accY[i][j][r] = v;
        s1 += v;
        s2 += v * v;
      }
      s1 += __shfl_xor(s1, 1); s2 += __shfl_xor(s2, 1);
      s1 += __shfl_xor(s1, 2); s2 += __shfl_xor(s2, 2);
      s1 += __shfl_xor(s1, 4); s2 += __shfl_xor(s2, 4);
      s1 += __shfl_xor(s1, 8); s2 += __shfl_xor(s2, 8);
      if (l15 == 0) {
        *(float*)(smem + PSOFF + (m * 4 + wv) * 4) = s1;
        *(float*)(smem + PQOFF + (m * 4 + wv) * 4) = s2;
      }
    }
  __syncthreads();
  if (tid < 96) {
    float s = 0.f, q = 0.f;
#pragma unroll
    for (int j = 0; j < 4; ++j) {
      s += *(const float*)(smem + PSOFF + (tid * 4 + j) * 4);
      q += *(const float*)(smem + PQOFF + (tid * 4 + j) * 4);
    }
    float mu  = s * (1.f / 256.f);
    float var = q * (1.f / 256.f) - mu * mu;
    *(float*)(smem + MUOFF + tid * 4) = mu;
    *(float*)(smem + RSOFF + tid * 4) = rsqrtf(var + 1e-5f);
  }
  __syncthreads();
  // rescale + write y bf16 into [32][768] swz (aliases x; all x reads done)
#pragma unroll
  for (int i = 0; i < 6; ++i)
#pragma unroll
    for (int r = 0; r < 4; ++r) {
      int m = i * 16 + l4 * 4 + r;
      float mu = *(const float*)(smem + MUOFF + m * 4);
      float rs = *(const float*)(smem + RSOFF + m * 4);
      int s = m >> 5, p = m & 31;
#pragma unroll
      for (int j = 0; j < 4; ++j) {
        int jc = wv * 64 + j * 16 + l15;
        float yv = (accY[i][j][r] - mu) * rs * gg[j] + bb2[j];
        int kk = s * 256 + jc;
        unsigned off = ((unsigned)(p * 1536 + kk * 2)) ^ ((unsigned)(p & 31) << 4);
        *(__bf16*)(smem + XOFF + off) = (__bf16)yv;
      }
    }
  __syncthreads();

  // ---------- 1x1 conv: M=cout(256, wave owns 64), N=pixel(32), K=768 ----------
  // 1-deep software pipeline: prefetch ks+1's w_conv fragments before ks's MFMAs (r16 win).
  {
    f32x4 accC[4][2] = {};
#pragma unroll 4
    for (int ks = 0; ks < 24; ++ks) {
      const int k0 = ks * 32;
      bf16x8 afn[4], bfr2[2];
      if (ks < 23) {
#pragma unroll
        for (int i = 0; i < 4; ++i) {
          int co = wv * 64 + i * 16 + l15;
          afn[i] = *(const bf16x8*)(w_conv + (size_t)co * 768 + (k0 + 32) + l4 * 8);
        }
      }
#pragma unroll
      for (int j = 0; j < 2; ++j) {
        int p = j * 16 + l15;
        unsigned off = ((unsigned)(p * 1536 + (k0 + l4 * 8) * 2)) ^ ((unsigned)(p & 31) << 4);
        bfr2[j] = *(const bf16x8*)(smem + XOFF + off);
      }
#pragma unroll
      for (int i = 0; i < 4; ++i)
#pragma unroll
        for (int j = 0; j < 2; ++j)
          accC[i][j] = __builtin_amdgcn_mfma_f32_16x16x32_bf16(cafp[i], bfr2[j], accC[i][j], 0, 0, 0);
      if (ks < 23) {
#pragma unroll
        for (int i = 0; i < 4; ++i) cafp[i] = afn[i];
      }
    }
#pragma unroll
    for (int i = 0; i < 4; ++i)
#pragma unroll
      for (int r = 0; r < 4; ++r) {
        int co = wv * 64 + i * 16 + l4 * 4 + r;
        float cb = b_conv[co];
#pragma unroll
        for (int j = 0; j < 2; ++j)
          out[((size_t)img * 256 + co) * 4096 + pixbase + j * 16 + l15] = accC[i][j][r] + cb;
      }
  }
}

extern "C" void kernel_launch(void* const* d_in, const int* in_sizes, int n_in,
                              void* d_out, int out_size, void* d_ws, size_t ws_size,
                              hipStream_t stream) {
  (void)in_sizes; (void)n_in; (void)out_size; (void)ws_size;
  const float* cort    = (const float*)d_in[0];
  const float* subc    = (const float*)d_in[1];
  const float* vent    = (const float*)d_in[2];
  const float* w_in_f  = (const float*)d_in[3];
  const float* b_in    = (const float*)d_in[4];
  const float* w_out_f = (const float*)d_in[5];
  const float* b_out   = (const float*)d_in[6];
  const float* gamma   = (const float*)d_in[7];
  const float* beta    = (const float*)d_in[8];
  const float* w_conv_f= (const float*)d_in[9];
  const float* b_conv  = (const float*)d_in[10];

  __bf16* ws = (__bf16*)d_ws;   // 458752 bf16 = 917504 B
  convert_weights<<<448, 256, 0, stream>>>(w_in_f, w_out_f, w_conv_f, ws);
  crf_fused<<<1024, 256, SMEM_BYTES, stream>>>(
      cort, subc, vent,
      ws,            b_in,
      ws + 196608,   b_out,
      gamma,         beta,
      ws + 262144,   b_conv,
      (float*)d_out);
}